// Round 10
// baseline (286.569 us; speedup 1.0000x reference)
//
#include <hip/hip_runtime.h>
#include <math.h>

#define TOKENS 4096
#define DMODEL 768
#define NHEADS 12
#define HDIM   64
#define QKV_N  2304          // 3*DMODEL
#define ATTN_SCALE 0.125f    // HDIM^-0.5
// fold log2(e) into Q so softmax uses v_exp_f32 (2^x) directly
#define QSCALE_LOG2E (0.125f * 1.44269504088896340736f)

typedef __attribute__((ext_vector_type(8))) short bf16x8;   // 8 bf16 = 4 VGPRs
typedef __attribute__((ext_vector_type(4))) float floatx4;

__device__ __forceinline__ ushort f2bf(float f) {
    union { float f; unsigned u; } cv; cv.f = f;
    unsigned u = cv.u;
    u += 0x7fffu + ((u >> 16) & 1u);   // round-to-nearest-even
    return (ushort)(u >> 16);
}

// pack two fp32 -> two bf16 (RNE) in one dword via v_perm_b32
__device__ __forceinline__ unsigned pack_bf16_rne(float a, float b) {
    union { float f; unsigned u; } ca, cb; ca.f = a; cb.f = b;
    unsigned ua = ca.u + 0x7fffu + ((ca.u >> 16) & 1u);
    unsigned ub = cb.u + 0x7fffu + ((cb.u >> 16) & 1u);
    return __builtin_amdgcn_perm(ub, ua, 0x07060302);   // lo16=hi(ua), hi16=hi(ub)
}

// async 16B global->LDS (lane i lands at ldsbase + i*16)
__device__ __forceinline__ void gl2lds16(const ushort* g, ushort* l) {
    __builtin_amdgcn_global_load_lds(
        (const __attribute__((address_space(1))) void*)g,
        (__attribute__((address_space(3))) void*)l, 16, 0, 0);
}

// fragment read: logical chunk c of row r lives at physical (c ^ (r&7))
__device__ __forceinline__ bf16x8 frag(const ushort* ls, int row, int chunk) {
    return *(const bf16x8*)(ls + row * 64 + ((chunk ^ (row & 7)) * 8));
}

// ---------------------------------------------------------------------------
// fp32 -> bf16 elementwise (x)
// ---------------------------------------------------------------------------
__global__ __launch_bounds__(256) void cvt_bf16_kernel(
    const float* __restrict__ in, ushort* __restrict__ out, int n4)
{
    const int i = blockIdx.x * 256 + threadIdx.x;
    if (i < n4) {
        const float4 v = ((const float4*)in)[i];
        ushort4 h;
        h.x = f2bf(v.x); h.y = f2bf(v.y); h.z = f2bf(v.z); h.w = f2bf(v.w);
        ((ushort4*)out)[i] = h;
    }
}

// ---------------------------------------------------------------------------
// fp32 [R][C] -> bf16 [C][R] transpose-convert (weights -> B^T operand layout)
// ---------------------------------------------------------------------------
__global__ __launch_bounds__(256) void transpose_cvt_kernel(
    const float* __restrict__ in, ushort* __restrict__ out, int R, int C)
{
    __shared__ ushort tile[32][33];
    const int tx  = threadIdx.x & 31;
    const int ty8 = threadIdx.x >> 5;           // 0..7
    const int c0 = blockIdx.x * 32;
    const int r0 = blockIdx.y * 32;
    #pragma unroll
    for (int p = 0; p < 4; ++p) {
        const int r = ty8 + p * 8;
        tile[r][tx] = f2bf(in[(size_t)(r0 + r) * C + c0 + tx]);
    }
    __syncthreads();
    #pragma unroll
    for (int p = 0; p < 4; ++p) {
        const int c = ty8 + p * 8;
        out[(size_t)(c0 + c) * R + r0 + tx] = tile[tx][c];
    }
}

// ---------------------------------------------------------------------------
// MFMA GEMM body (m97 recipe): 128 x (NT*32) tile, BK=64, 4 waves 2x2.
// Staging via global_load_lds width=16 with XOR-swizzled global chunk.
// ---------------------------------------------------------------------------
template<int NT>
__device__ __forceinline__ void gemm_body_async(
    const ushort* __restrict__ A, const ushort* __restrict__ Bt, int K,
    int m0, int n0, floatx4 acc[4][NT], ushort* ls)
{
    ushort* lsA = ls;
    ushort* lsB = ls + 8192;

    const int tid  = threadIdx.x;
    const int lane = tid & 63;
    const int wave = tid >> 6;
    const int wm = wave >> 1, wn = wave & 1;
    const int quad = lane >> 4, l16 = lane & 15;

    const int lrow = lane >> 3;          // 0..7
    const int csw  = ((lane & 7) ^ lrow) * 8;   // swizzled global chunk (ushorts)

    const ushort* gA = A  + (size_t)(m0 + wave * 32 + lrow) * K + csw;
    const ushort* gB = Bt + (size_t)(n0 + wave * NT * 8 + lrow) * K + csw;
    ushort* lA = lsA + (wave * 32) * 64;
    ushort* lB = lsB + (wave * NT * 8) * 64;

    for (int k0 = 0; k0 < K; k0 += 64) {
        __syncthreads();
        #pragma unroll
        for (int p = 0; p < 4; ++p)
            gl2lds16(gA + (size_t)p * 8 * K + k0, lA + p * 8 * 64);
        #pragma unroll
        for (int p = 0; p < NT; ++p)
            gl2lds16(gB + (size_t)p * 8 * K + k0, lB + p * 8 * 64);
        __syncthreads();

        #pragma unroll
        for (int ks = 0; ks < 2; ++ks) {
            bf16x8 af[4], bfr[NT];
            #pragma unroll
            for (int mt = 0; mt < 4; ++mt)
                af[mt] = frag(lsA, wm * 64 + mt * 16 + l16, ks * 4 + quad);
            #pragma unroll
            for (int nt = 0; nt < NT; ++nt)
                bfr[nt] = frag(lsB, wn * NT * 16 + nt * 16 + l16, ks * 4 + quad);
            #pragma unroll
            for (int mt = 0; mt < 4; ++mt)
                #pragma unroll
                for (int nt = 0; nt < NT; ++nt)
                    acc[mt][nt] = __builtin_amdgcn_mfma_f32_16x16x32_bf16(
                        af[mt], bfr[nt], acc[mt][nt], 0, 0, 0);
        }
    }
}

// ---------------------------------------------------------------------------
// qkv GEMM: 128x128 tiles. Epilogue re-tiles through LDS (stride 136) so
// every store instruction writes 256B contiguous per 16 lanes.
// ---------------------------------------------------------------------------
__global__ __launch_bounds__(256) void gemm_qkv_mfma(
    const ushort* __restrict__ Xb, const ushort* __restrict__ Wt,
    ushort* __restrict__ Qb, ushort* __restrict__ Kb, ushort* __restrict__ Vt)
{
    __shared__ __align__(16) ushort ls[16384];   // 32 KB: GEMM tiles + retile
    const int m0 = blockIdx.y * 128;
    const int n0 = blockIdx.x * 128;

    floatx4 acc[4][4] = {};
    gemm_body_async<4>(Xb, Wt, DMODEL, m0, n0, acc, ls);

    const int tid  = threadIdx.x;
    const int lane = tid & 63;
    const int wave = tid >> 6;
    const int wm = wave >> 1, wn = wave & 1;
    const int quad = lane >> 4, l16 = lane & 15;

    if (n0 < 2 * DMODEL) {
        // ---- Q or K: two passes over 64-row halves ----
        const float scale = (n0 < DMODEL) ? QSCALE_LOG2E : 1.0f;
        ushort* outp = (n0 < DMODEL) ? Qb : Kb;
        const int colg = (n0 < DMODEL) ? n0 : n0 - DMODEL;
        #pragma unroll
        for (int p = 0; p < 2; ++p) {
            __syncthreads();
            if (wm == p) {
                #pragma unroll
                for (int mt = 0; mt < 4; ++mt)
                    #pragma unroll
                    for (int nt = 0; nt < 4; ++nt) {
                        const int row = mt * 16 + quad * 4;
                        const int col = wn * 64 + nt * 16 + l16;
                        #pragma unroll
                        for (int r = 0; r < 4; ++r)
                            ls[(row + r) * 136 + col] = f2bf(acc[mt][nt][r] * scale);
                    }
            }
            __syncthreads();
            #pragma unroll
            for (int p2 = 0; p2 < 4; ++p2) {
                const int row = (tid >> 4) + p2 * 16;
                const int c8  = (tid & 15) * 8;
                *(uint4*)(outp + (size_t)(m0 + p * 64 + row) * DMODEL + colg + c8) =
                    *(const uint4*)(ls + row * 136 + c8);
            }
        }
    } else {
        // ---- V transposed: two passes over 64-hd halves ----
        const int hd0 = n0 - 2 * DMODEL;
        #pragma unroll
        for (int p = 0; p < 2; ++p) {
            __syncthreads();
            if (wn == p) {
                #pragma unroll
                for (int mt = 0; mt < 4; ++mt)
                    #pragma unroll
                    for (int nt = 0; nt < 4; ++nt) {
                        const int hd  = nt * 16 + l16;
                        const int tok = wm * 64 + mt * 16 + quad * 4;
                        #pragma unroll
                        for (int r = 0; r < 4; ++r)
                            ls[hd * 136 + tok + r] = f2bf(acc[mt][nt][r]);
                    }
            }
            __syncthreads();
            #pragma unroll
            for (int p2 = 0; p2 < 4; ++p2) {
                const int row = (tid >> 4) + p2 * 16;    // local hd
                const int c8  = (tid & 15) * 8;          // token chunk
                *(uint4*)(Vt + (size_t)(hd0 + p * 64 + row) * TOKENS + m0 + c8) =
                    *(const uint4*)(ls + row * 136 + c8);
            }
        }
    }
}

// ---------------------------------------------------------------------------
// proj GEMM: 128x64 tiles (grid 384), direct fp32 stores (full 64B sectors).
// ---------------------------------------------------------------------------
__global__ __launch_bounds__(256) void gemm_proj_mfma(
    const ushort* __restrict__ Ab, const ushort* __restrict__ Wt,
    const float* __restrict__ bias, float* __restrict__ out)
{
    __shared__ __align__(16) ushort ls[12288];   // 16 KB A + 8 KB B
    const int m0 = blockIdx.y * 128;
    const int n0 = blockIdx.x * 64;

    floatx4 acc[4][2] = {};
    gemm_body_async<2>(Ab, Wt, DMODEL, m0, n0, acc, ls);

    const int lane = threadIdx.x & 63;
    const int wave = threadIdx.x >> 6;
    const int wm = wave >> 1, wn = wave & 1;
    const int quad = lane >> 4, l16 = lane & 15;
    const int row0 = m0 + wm * 64 + quad * 4;
    const int col0 = n0 + wn * 32;

    #pragma unroll
    for (int nt = 0; nt < 2; ++nt) {
        const int col = col0 + nt * 16 + l16;
        const float bv = bias[col];
        #pragma unroll
        for (int mt = 0; mt < 4; ++mt)
            #pragma unroll
            for (int r = 0; r < 4; ++r)
                out[(size_t)(row0 + mt * 16 + r) * DMODEL + col] =
                    acc[mt][nt][r] + bv;
    }
}

// ---------------------------------------------------------------------------
// Fat-wave x2 MFMA flash attention: block = 2 waves of 64 lanes; each wave
// owns a 64-query tile (Q/O/Ol register-resident), the two waves SHARE the
// K/V chunk buffers (halves LDS fragment-read duplication vs 4 thin waves,
// but keeps >=2 waves/block for cross-wave pipe overlap — fixes R9's
// 1-wave/SIMD starvation). R8-proven sync: one barrier per chunk, prefetch
// DMA issued after the barrier so it drains for free at the next one.
// ---------------------------------------------------------------------------
__global__ __launch_bounds__(128) void attn_mfma_kernel(
    const ushort* __restrict__ Qb, const ushort* __restrict__ Kb,
    const ushort* __restrict__ Vt, ushort* __restrict__ attn_out)
{
    // ushort offsets: K0 @0, K1 @4096, V0 @8192, V1 @12288, P @16384+wave*4096
    __shared__ __align__(16) ushort lds[24576];   // 48 KB

    const int tid  = threadIdx.x;
    const int wave = tid >> 6;           // 0..1
    const int lane = tid & 63;
    const int quad = lane >> 4;
    const int l16  = lane & 15;
    const int h    = blockIdx.y;
    const int i0   = blockIdx.x * 128 + wave * 64;   // this wave's 64-query tile

    // ---- Q: 64 rows x 64 k, register resident (B-operand frags) ----
    bf16x8 qf[4][2];
    #pragma unroll
    for (int qt = 0; qt < 4; ++qt)
        #pragma unroll
        for (int ks = 0; ks < 2; ++ks)
            qf[qt][ks] = *(const bf16x8*)(Qb +
                (size_t)(i0 + qt * 16 + l16) * DMODEL + h * HDIM + ks * 32 + quad * 8);

    bf16x8 ones;
    #pragma unroll
    for (int i = 0; i < 8; ++i) ones[i] = (short)0x3F80;   // bf16 1.0

    floatx4 O[4][4];
    #pragma unroll
    for (int mt = 0; mt < 4; ++mt)
        #pragma unroll
        for (int nt = 0; nt < 4; ++nt) O[mt][nt] = (floatx4){0.f, 0.f, 0.f, 0.f};
    floatx4 Ol[4];
    #pragma unroll
    for (int mt = 0; mt < 4; ++mt) Ol[mt] = (floatx4){0.f, 0.f, 0.f, 0.f};

    ushort* Pb = lds + 16384 + wave * 4096;   // per-wave P (64x64 bf16)

    // staging: wave w stages K/V rows w*32..w*32+31 (8 DMA issues per wave)
    const int lrow = lane >> 3;
    const int csw  = ((lane & 7) ^ lrow) * 8;
    const int srow = wave * 32 + lrow;
    const ushort* gK = Kb + (size_t)srow * DMODEL + h * HDIM + csw;
    const ushort* gV = Vt + (size_t)(h * HDIM + srow) * TOKENS + csw;

    // prologue: stage chunk 0 into buffer 0
    #pragma unroll
    for (int p = 0; p < 4; ++p) {
        gl2lds16(gK + (size_t)p * 8 * DMODEL, lds + (srow + p * 8) * 64);
        gl2lds16(gV + (size_t)p * 8 * TOKENS, lds + 8192 + (srow + p * 8) * 64);
    }

    for (int j0 = 0; j0 < TOKENS; j0 += 64) {
        const int cur = (j0 >> 6) & 1;
        const ushort* Ks = lds + cur * 4096;
        const ushort* Vs = lds + 8192 + cur * 4096;

        __syncthreads();   // buf[cur] DMA landed; both waves done with spare

        if (j0 + 64 < TOKENS) {   // prefetch next chunk into the spare buffer
            ushort* Kn = lds + (1 - cur) * 4096;
            ushort* Vn = lds + 8192 + (1 - cur) * 4096;
            #pragma unroll
            for (int p = 0; p < 4; ++p) {
                gl2lds16(gK + (size_t)(j0 + 64) * DMODEL + (size_t)p * 8 * DMODEL,
                         Kn + (srow + p * 8) * 64);
                gl2lds16(gV + (size_t)(j0 + 64) + (size_t)p * 8 * TOKENS,
                         Vn + (srow + p * 8) * 64);
            }
        }

        // ---- S^T = K * Q^T : 4 key-tiles x 4 query-tiles ----
        floatx4 Sv[4][4];
        #pragma unroll
        for (int jt = 0; jt < 4; ++jt) {
            const bf16x8 k0 = frag(Ks, jt * 16 + l16, quad);
            const bf16x8 k1 = frag(Ks, jt * 16 + l16, 4 + quad);
            #pragma unroll
            for (int qt = 0; qt < 4; ++qt) {
                floatx4 s = {0.f, 0.f, 0.f, 0.f};
                s = __builtin_amdgcn_mfma_f32_16x16x32_bf16(k0, qf[qt][0], s, 0, 0, 0);
                s = __builtin_amdgcn_mfma_f32_16x16x32_bf16(k1, qf[qt][1], s, 0, 0, 0);
                Sv[jt][qt] = s;
            }
        }

        // ---- p = 2^s, pack bf16, write P (A-layout, swizzled, wave-private) --
        #pragma unroll
        for (int jt = 0; jt < 4; ++jt)
            #pragma unroll
            for (int qt = 0; qt < 4; ++qt) {
                const float p0 = __builtin_amdgcn_exp2f(Sv[jt][qt][0]);
                const float p1 = __builtin_amdgcn_exp2f(Sv[jt][qt][1]);
                const float p2 = __builtin_amdgcn_exp2f(Sv[jt][qt][2]);
                const float p3 = __builtin_amdgcn_exp2f(Sv[jt][qt][3]);
                uint2 val;
                val.x = pack_bf16_rne(p0, p1);
                val.y = pack_bf16_rne(p2, p3);
                const int q = qt * 16 + l16;
                const int c = jt * 2 + (quad >> 1);
                *(uint2*)(Pb + (q * 8 + (c ^ (q & 7))) * 8 + (quad & 1) * 4) = val;
            }

        // ---- P fragments (A-operand) ----
        bf16x8 pf[4][2];
        #pragma unroll
        for (int mt = 0; mt < 4; ++mt) {
            pf[mt][0] = frag(Pb, mt * 16 + l16, quad);
            pf[mt][1] = frag(Pb, mt * 16 + l16, 4 + quad);
        }

        // ---- l += P * 1 (row-aligned with O accs) ----
        #pragma unroll
        for (int mt = 0; mt < 4; ++mt) {
            Ol[mt] = __builtin_amdgcn_mfma_f32_16x16x32_bf16(pf[mt][0], ones, Ol[mt], 0, 0, 0);
            Ol[mt] = __builtin_amdgcn_mfma_f32_16x16x32_bf16(pf[mt][1], ones, Ol[mt], 0, 0, 0);
        }

        // ---- O += P * V ----
        #pragma unroll
        for (int nt = 0; nt < 4; ++nt) {
            const bf16x8 v0 = frag(Vs, nt * 16 + l16, quad);
            const bf16x8 v1 = frag(Vs, nt * 16 + l16, 4 + quad);
            #pragma unroll
            for (int mt = 0; mt < 4; ++mt) {
                O[mt][nt] = __builtin_amdgcn_mfma_f32_16x16x32_bf16(pf[mt][0], v0, O[mt][nt], 0, 0, 0);
                O[mt][nt] = __builtin_amdgcn_mfma_f32_16x16x32_bf16(pf[mt][1], v1, O[mt][nt], 0, 0, 0);
            }
        }
    }

    // ---- epilogue: O / l, store bf16 ----
    #pragma unroll
    for (int mt = 0; mt < 4; ++mt) {
        float linv[4];
        #pragma unroll
        for (int r = 0; r < 4; ++r) linv[r] = __builtin_amdgcn_rcpf(Ol[mt][r]);
        const int row0 = i0 + mt * 16 + quad * 4;
        #pragma unroll
        for (int nt = 0; nt < 4; ++nt) {
            const int d = h * HDIM + nt * 16 + l16;
            #pragma unroll
            for (int r = 0; r < 4; ++r)
                attn_out[(size_t)(row0 + r) * DMODEL + d] = f2bf(O[mt][nt][r] * linv[r]);
        }
    }
}

// ---------------------------------------------------------------------------
extern "C" void kernel_launch(void* const* d_in, const int* in_sizes, int n_in,
                              void* d_out, int out_size, void* d_ws, size_t ws_size,
                              hipStream_t stream)
{
    const float* x     = (const float*)d_in[0];
    const float* Wqkv  = (const float*)d_in[1];
    const float* Wproj = (const float*)d_in[2];
    const float* bproj = (const float*)d_in[3];
    float* out = (float*)d_out;

    ushort* Xb     = (ushort*)d_ws;                          // [4096][768]
    ushort* WqkvT  = Xb    + (size_t)TOKENS * DMODEL;        // [2304][768]
    ushort* WprojT = WqkvT + (size_t)QKV_N * DMODEL;         // [768][768]
    ushort* Qb     = WprojT + (size_t)DMODEL * DMODEL;       // [4096][768]
    ushort* Kb     = Qb    + (size_t)TOKENS * DMODEL;        // [4096][768]
    ushort* Vt     = Kb    + (size_t)TOKENS * DMODEL;        // [768][4096]
    ushort* attn   = Vt    + (size_t)TOKENS * DMODEL;        // [4096][768]

    cvt_bf16_kernel<<<dim3(TOKENS * DMODEL / 4 / 256), 256, 0, stream>>>(
        x, Xb, TOKENS * DMODEL / 4);
    transpose_cvt_kernel<<<dim3(QKV_N / 32, DMODEL / 32), 256, 0, stream>>>(
        Wqkv, WqkvT, DMODEL, QKV_N);
    transpose_cvt_kernel<<<dim3(DMODEL / 32, DMODEL / 32), 256, 0, stream>>>(
        Wproj, WprojT, DMODEL, DMODEL);

    gemm_qkv_mfma<<<dim3(QKV_N / 128, TOKENS / 128), 256, 0, stream>>>(
        Xb, WqkvT, Qb, Kb, Vt);

    attn_mfma_kernel<<<dim3(TOKENS / 128, NHEADS), 128, 0, stream>>>(
        Qb, Kb, Vt, attn);

    gemm_proj_mfma<<<dim3(DMODEL / 64, TOKENS / 128), 256, 0, stream>>>(
        attn, WprojT, bproj, out);
}

// Round 11
// 221.562 us; speedup vs baseline: 1.2934x; 1.2934x over previous
//
#include <hip/hip_runtime.h>
#include <math.h>

#define TOKENS 4096
#define DMODEL 768
#define NHEADS 12
#define HDIM   64
#define QKV_N  2304          // 3*DMODEL
#define ATTN_SCALE 0.125f    // HDIM^-0.5
// fold log2(e) into Q so softmax uses v_exp_f32 (2^x) directly
#define QSCALE_LOG2E (0.125f * 1.44269504088896340736f)

#if defined(__has_builtin)
#if __has_builtin(__builtin_amdgcn_mfma_f32_16x16x16bf16_1k)
#define HAVE_MFMA16 1
#endif
#endif

typedef __attribute__((ext_vector_type(8))) short bf16x8;   // 8 bf16 = 4 VGPRs
typedef __attribute__((ext_vector_type(4))) short bf16x4;   // 4 bf16 = 2 VGPRs
typedef __attribute__((ext_vector_type(4))) float floatx4;

__device__ __forceinline__ ushort f2bf(float f) {
    union { float f; unsigned u; } cv; cv.f = f;
    unsigned u = cv.u;
    u += 0x7fffu + ((u >> 16) & 1u);   // round-to-nearest-even
    return (ushort)(u >> 16);
}

// pack two fp32 -> two bf16 (RNE) in one dword via v_perm_b32
__device__ __forceinline__ unsigned pack_bf16_rne(float a, float b) {
    union { float f; unsigned u; } ca, cb; ca.f = a; cb.f = b;
    unsigned ua = ca.u + 0x7fffu + ((ca.u >> 16) & 1u);
    unsigned ub = cb.u + 0x7fffu + ((cb.u >> 16) & 1u);
    return __builtin_amdgcn_perm(ub, ua, 0x07060302);   // lo16=hi(ua), hi16=hi(ub)
}

// async 16B global->LDS (lane i lands at ldsbase + i*16)
__device__ __forceinline__ void gl2lds16(const ushort* g, ushort* l) {
    __builtin_amdgcn_global_load_lds(
        (const __attribute__((address_space(1))) void*)g,
        (__attribute__((address_space(3))) void*)l, 16, 0, 0);
}

// b128 fragment read: logical chunk c of row r lives at physical (c ^ (r&7))
__device__ __forceinline__ bf16x8 frag(const ushort* ls, int row, int chunk) {
    return *(const bf16x8*)(ls + row * 64 + ((chunk ^ (row & 7)) * 8));
}

// b64 fragment read (half of a 16B chunk)
__device__ __forceinline__ bf16x4 frag64(const ushort* ls, int row, int chunk, int half) {
    return *(const bf16x4*)(ls + row * 64 + ((chunk ^ (row & 7)) * 8) + half * 4);
}

// ---------------------------------------------------------------------------
// fp32 -> bf16 elementwise (x)
// ---------------------------------------------------------------------------
__global__ __launch_bounds__(256) void cvt_bf16_kernel(
    const float* __restrict__ in, ushort* __restrict__ out, int n4)
{
    const int i = blockIdx.x * 256 + threadIdx.x;
    if (i < n4) {
        const float4 v = ((const float4*)in)[i];
        ushort4 h;
        h.x = f2bf(v.x); h.y = f2bf(v.y); h.z = f2bf(v.z); h.w = f2bf(v.w);
        ((ushort4*)out)[i] = h;
    }
}

// ---------------------------------------------------------------------------
// fp32 [R][C] -> bf16 [C][R] transpose-convert (weights -> B^T operand layout)
// ---------------------------------------------------------------------------
__global__ __launch_bounds__(256) void transpose_cvt_kernel(
    const float* __restrict__ in, ushort* __restrict__ out, int R, int C)
{
    __shared__ ushort tile[32][33];
    const int tx  = threadIdx.x & 31;
    const int ty8 = threadIdx.x >> 5;           // 0..7
    const int c0 = blockIdx.x * 32;
    const int r0 = blockIdx.y * 32;
    #pragma unroll
    for (int p = 0; p < 4; ++p) {
        const int r = ty8 + p * 8;
        tile[r][tx] = f2bf(in[(size_t)(r0 + r) * C + c0 + tx]);
    }
    __syncthreads();
    #pragma unroll
    for (int p = 0; p < 4; ++p) {
        const int c = ty8 + p * 8;
        out[(size_t)(c0 + c) * R + r0 + tx] = tile[tx][c];
    }
}

// ---------------------------------------------------------------------------
// MFMA GEMM body (m97 recipe): 128 x (NT*32) tile, BK=64, 4 waves 2x2.
// Staging via global_load_lds width=16 with XOR-swizzled global chunk.
// ---------------------------------------------------------------------------
template<int NT>
__device__ __forceinline__ void gemm_body_async(
    const ushort* __restrict__ A, const ushort* __restrict__ Bt, int K,
    int m0, int n0, floatx4 acc[4][NT], ushort* ls)
{
    ushort* lsA = ls;
    ushort* lsB = ls + 8192;

    const int tid  = threadIdx.x;
    const int lane = tid & 63;
    const int wave = tid >> 6;
    const int wm = wave >> 1, wn = wave & 1;
    const int quad = lane >> 4, l16 = lane & 15;

    const int lrow = lane >> 3;          // 0..7
    const int csw  = ((lane & 7) ^ lrow) * 8;   // swizzled global chunk (ushorts)

    const ushort* gA = A  + (size_t)(m0 + wave * 32 + lrow) * K + csw;
    const ushort* gB = Bt + (size_t)(n0 + wave * NT * 8 + lrow) * K + csw;
    ushort* lA = lsA + (wave * 32) * 64;
    ushort* lB = lsB + (wave * NT * 8) * 64;

    for (int k0 = 0; k0 < K; k0 += 64) {
        __syncthreads();
        #pragma unroll
        for (int p = 0; p < 4; ++p)
            gl2lds16(gA + (size_t)p * 8 * K + k0, lA + p * 8 * 64);
        #pragma unroll
        for (int p = 0; p < NT; ++p)
            gl2lds16(gB + (size_t)p * 8 * K + k0, lB + p * 8 * 64);
        __syncthreads();

        #pragma unroll
        for (int ks = 0; ks < 2; ++ks) {
            bf16x8 af[4], bfr[NT];
            #pragma unroll
            for (int mt = 0; mt < 4; ++mt)
                af[mt] = frag(lsA, wm * 64 + mt * 16 + l16, ks * 4 + quad);
            #pragma unroll
            for (int nt = 0; nt < NT; ++nt)
                bfr[nt] = frag(lsB, wn * NT * 16 + nt * 16 + l16, ks * 4 + quad);
            #pragma unroll
            for (int mt = 0; mt < 4; ++mt)
                #pragma unroll
                for (int nt = 0; nt < NT; ++nt)
                    acc[mt][nt] = __builtin_amdgcn_mfma_f32_16x16x32_bf16(
                        af[mt], bfr[nt], acc[mt][nt], 0, 0, 0);
        }
    }
}

// ---------------------------------------------------------------------------
// qkv GEMM: 128x128 tiles. Epilogue re-tiles through LDS (stride 136) so
// every store instruction writes 256B contiguous per 16 lanes.
// ---------------------------------------------------------------------------
__global__ __launch_bounds__(256) void gemm_qkv_mfma(
    const ushort* __restrict__ Xb, const ushort* __restrict__ Wt,
    ushort* __restrict__ Qb, ushort* __restrict__ Kb, ushort* __restrict__ Vt)
{
    __shared__ __align__(16) ushort ls[16384];   // 32 KB: GEMM tiles + retile
    const int m0 = blockIdx.y * 128;
    const int n0 = blockIdx.x * 128;

    floatx4 acc[4][4] = {};
    gemm_body_async<4>(Xb, Wt, DMODEL, m0, n0, acc, ls);

    const int tid  = threadIdx.x;
    const int lane = tid & 63;
    const int wave = tid >> 6;
    const int wm = wave >> 1, wn = wave & 1;
    const int quad = lane >> 4, l16 = lane & 15;

    if (n0 < 2 * DMODEL) {
        // ---- Q or K: two passes over 64-row halves ----
        const float scale = (n0 < DMODEL) ? QSCALE_LOG2E : 1.0f;
        ushort* outp = (n0 < DMODEL) ? Qb : Kb;
        const int colg = (n0 < DMODEL) ? n0 : n0 - DMODEL;
        #pragma unroll
        for (int p = 0; p < 2; ++p) {
            __syncthreads();
            if (wm == p) {
                #pragma unroll
                for (int mt = 0; mt < 4; ++mt)
                    #pragma unroll
                    for (int nt = 0; nt < 4; ++nt) {
                        const int row = mt * 16 + quad * 4;
                        const int col = wn * 64 + nt * 16 + l16;
                        #pragma unroll
                        for (int r = 0; r < 4; ++r)
                            ls[(row + r) * 136 + col] = f2bf(acc[mt][nt][r] * scale);
                    }
            }
            __syncthreads();
            #pragma unroll
            for (int p2 = 0; p2 < 4; ++p2) {
                const int row = (tid >> 4) + p2 * 16;
                const int c8  = (tid & 15) * 8;
                *(uint4*)(outp + (size_t)(m0 + p * 64 + row) * DMODEL + colg + c8) =
                    *(const uint4*)(ls + row * 136 + c8);
            }
        }
    } else {
        // ---- V transposed: two passes over 64-hd halves ----
        const int hd0 = n0 - 2 * DMODEL;
        #pragma unroll
        for (int p = 0; p < 2; ++p) {
            __syncthreads();
            if (wn == p) {
                #pragma unroll
                for (int mt = 0; mt < 4; ++mt)
                    #pragma unroll
                    for (int nt = 0; nt < 4; ++nt) {
                        const int hd  = nt * 16 + l16;
                        const int tok = wm * 64 + mt * 16 + quad * 4;
                        #pragma unroll
                        for (int r = 0; r < 4; ++r)
                            ls[hd * 136 + tok + r] = f2bf(acc[mt][nt][r]);
                    }
            }
            __syncthreads();
            #pragma unroll
            for (int p2 = 0; p2 < 4; ++p2) {
                const int row = (tid >> 4) + p2 * 16;    // local hd
                const int c8  = (tid & 15) * 8;          // token chunk
                *(uint4*)(Vt + (size_t)(hd0 + p * 64 + row) * TOKENS + m0 + c8) =
                    *(const uint4*)(ls + row * 136 + c8);
            }
        }
    }
}

// ---------------------------------------------------------------------------
// proj GEMM: 128x64 tiles (grid 384), direct fp32 stores (full 64B sectors).
// ---------------------------------------------------------------------------
__global__ __launch_bounds__(256) void gemm_proj_mfma(
    const ushort* __restrict__ Ab, const ushort* __restrict__ Wt,
    const float* __restrict__ bias, float* __restrict__ out)
{
    __shared__ __align__(16) ushort ls[12288];   // 16 KB A + 8 KB B
    const int m0 = blockIdx.y * 128;
    const int n0 = blockIdx.x * 64;

    floatx4 acc[4][2] = {};
    gemm_body_async<2>(Ab, Wt, DMODEL, m0, n0, acc, ls);

    const int lane = threadIdx.x & 63;
    const int wave = threadIdx.x >> 6;
    const int wm = wave >> 1, wn = wave & 1;
    const int quad = lane >> 4, l16 = lane & 15;
    const int row0 = m0 + wm * 64 + quad * 4;
    const int col0 = n0 + wn * 32;

    #pragma unroll
    for (int nt = 0; nt < 2; ++nt) {
        const int col = col0 + nt * 16 + l16;
        const float bv = bias[col];
        #pragma unroll
        for (int mt = 0; mt < 4; ++mt)
            #pragma unroll
            for (int r = 0; r < 4; ++r)
                out[(size_t)(row0 + mt * 16 + r) * DMODEL + col] =
                    acc[mt][nt][r] + bv;
    }
}

// ---------------------------------------------------------------------------
// MFMA flash attention (R8 structure: 4 waves x 16 queries, 768 blocks,
// double-buffered K/V DMA, one barrier per chunk) with IN-REGISTER P:
// S^T's C-layout (lane holds keys quad*4+r for query l16) is exactly the
// A-operand layout of the K=16 MFMA, so PV and the l-sum run on
// mfma_f32_16x16x16bf16_1k with P packed straight from the exp results —
// no P LDS round-trip, no lgkmcnt serialization. V read as b64 B-fragments.
// Fallback (no 1k builtin): R8's LDS round-trip path.
// ---------------------------------------------------------------------------
__global__ __launch_bounds__(256) void attn_mfma_kernel(
    const ushort* __restrict__ Qb, const ushort* __restrict__ Kb,
    const ushort* __restrict__ Vt, ushort* __restrict__ attn_out)
{
#ifdef HAVE_MFMA16
    // K0 @0, K1 @4096, V0 @8192, V1 @12288 (32 KB)
    __shared__ __align__(16) ushort lds[16384];
#else
    // + P @16384 (40 KB)
    __shared__ __align__(16) ushort lds[20480];
#endif

    const int tid  = threadIdx.x;
    const int wave = tid >> 6;
    const int lane = tid & 63;
    const int quad = lane >> 4;
    const int l16  = lane & 15;
    const int h    = blockIdx.y;
    const int i0   = blockIdx.x * 64;

    // Q fragments (B-operand of 16x16x32), register-resident
    const ushort* qbase = Qb + (size_t)(i0 + wave * 16 + l16) * DMODEL + h * HDIM;
    const bf16x8 qf0 = *(const bf16x8*)(qbase + quad * 8);
    const bf16x8 qf1 = *(const bf16x8*)(qbase + 32 + quad * 8);

    floatx4 O[4] = {{0.f,0.f,0.f,0.f},{0.f,0.f,0.f,0.f},{0.f,0.f,0.f,0.f},{0.f,0.f,0.f,0.f}};
    floatx4 Ol = {0.f, 0.f, 0.f, 0.f};      // row-sums (softmax denominator)

    // staging: wave w stages K/V rows w*16 .. w*16+15
    const int lrow = lane >> 3;
    const int csw  = ((lane & 7) ^ lrow) * 8;
    const ushort* gK = Kb + (size_t)(wave * 16 + lrow) * DMODEL + h * HDIM + csw;
    const ushort* gV = Vt + (size_t)(h * HDIM + wave * 16 + lrow) * TOKENS + csw;

    // prologue: stage chunk 0 into buffer 0
    #pragma unroll
    for (int p = 0; p < 2; ++p) {
        gl2lds16(gK + (size_t)p * 8 * DMODEL, lds + (wave * 16 + p * 8) * 64);
        gl2lds16(gV + (size_t)p * 8 * TOKENS, lds + 8192 + (wave * 16 + p * 8) * 64);
    }

#ifdef HAVE_MFMA16
    bf16x4 ones4;
    #pragma unroll
    for (int i = 0; i < 4; ++i) ones4[i] = (short)0x3F80;   // bf16 1.0
#else
    bf16x8 ones;
    #pragma unroll
    for (int i = 0; i < 8; ++i) ones[i] = (short)0x3F80;
    ushort* pw = lds + 16384 + wave * 1024 + l16 * 64;
    const int sw = (l16 & 7);
#endif

    for (int j0 = 0; j0 < TOKENS; j0 += 64) {
        const int cur = (j0 >> 6) & 1;
        const ushort* Ks = lds + cur * 4096;
        const ushort* Vs = lds + 8192 + cur * 4096;

        __syncthreads();   // buf[cur] DMA landed; all waves done with spare

        if (j0 + 64 < TOKENS) {   // prefetch next chunk into the spare buffer
            ushort* Kn = lds + (1 - cur) * 4096;
            ushort* Vn = lds + 8192 + (1 - cur) * 4096;
            #pragma unroll
            for (int p = 0; p < 2; ++p) {
                gl2lds16(gK + (size_t)(j0 + 64) * DMODEL + (size_t)p * 8 * DMODEL,
                         Kn + (wave * 16 + p * 8) * 64);
                gl2lds16(gV + (size_t)(j0 + 64) + (size_t)p * 8 * TOKENS,
                         Vn + (wave * 16 + p * 8) * 64);
            }
        }

        // ---- S^T = K * Q^T (log2-domain scores), 4 key-tiles of 16 ----
        floatx4 Sv[4];
        #pragma unroll
        for (int jt = 0; jt < 4; ++jt) {
            const bf16x8 k0 = frag(Ks, jt * 16 + l16, quad);
            const bf16x8 k1 = frag(Ks, jt * 16 + l16, 4 + quad);
            floatx4 s = {0.f, 0.f, 0.f, 0.f};
            s = __builtin_amdgcn_mfma_f32_16x16x32_bf16(k0, qf0, s, 0, 0, 0);
            s = __builtin_amdgcn_mfma_f32_16x16x32_bf16(k1, qf1, s, 0, 0, 0);
            Sv[jt] = s;
        }

#ifdef HAVE_MFMA16
        // ---- p = 2^s packed in-register: A-operand frags for K=16 MFMA ----
        bf16x4 pf[4];
        #pragma unroll
        for (int jt = 0; jt < 4; ++jt) {
            const float p0 = __builtin_amdgcn_exp2f(Sv[jt][0]);
            const float p1 = __builtin_amdgcn_exp2f(Sv[jt][1]);
            const float p2 = __builtin_amdgcn_exp2f(Sv[jt][2]);
            const float p3 = __builtin_amdgcn_exp2f(Sv[jt][3]);
            union { uint2 u; bf16x4 h; } cv;
            cv.u.x = pack_bf16_rne(p0, p1);
            cv.u.y = pack_bf16_rne(p2, p3);
            pf[jt] = cv.h;
        }

        // ---- l += P * 1 ----
        #pragma unroll
        for (int jt = 0; jt < 4; ++jt)
            Ol = __builtin_amdgcn_mfma_f32_16x16x16bf16_1k(pf[jt], ones4, Ol, 0, 0, 0);

        // ---- O += P * V  (V as b64 B-fragments: B[k=key][n=d]) ----
        #pragma unroll
        for (int nt = 0; nt < 4; ++nt)
            #pragma unroll
            for (int jt = 0; jt < 4; ++jt) {
                const bf16x4 v = frag64(Vs, nt * 16 + l16, jt * 2 + (quad >> 1), quad & 1);
                O[nt] = __builtin_amdgcn_mfma_f32_16x16x16bf16_1k(pf[jt], v, O[nt], 0, 0, 0);
            }
#else
        // ---- fallback: R8 LDS round-trip ----
        #pragma unroll
        for (int jt = 0; jt < 4; ++jt) {
            const float p0 = __builtin_amdgcn_exp2f(Sv[jt][0]);
            const float p1 = __builtin_amdgcn_exp2f(Sv[jt][1]);
            const float p2 = __builtin_amdgcn_exp2f(Sv[jt][2]);
            const float p3 = __builtin_amdgcn_exp2f(Sv[jt][3]);
            uint2 val;
            val.x = pack_bf16_rne(p0, p1);
            val.y = pack_bf16_rne(p2, p3);
            const int chunk = jt * 2 + (quad >> 1);
            *(uint2*)(pw + ((chunk ^ sw) * 8) + (quad & 1) * 4) = val;
        }
        const bf16x8 pf0 = *(const bf16x8*)(pw + ((quad ^ sw) * 8));
        const bf16x8 pf1 = *(const bf16x8*)(pw + (((4 + quad) ^ sw) * 8));
        Ol = __builtin_amdgcn_mfma_f32_16x16x32_bf16(pf0, ones, Ol, 0, 0, 0);
        Ol = __builtin_amdgcn_mfma_f32_16x16x32_bf16(pf1, ones, Ol, 0, 0, 0);
        #pragma unroll
        for (int nt = 0; nt < 4; ++nt) {
            const bf16x8 v0 = frag(Vs, nt * 16 + l16, quad);
            const bf16x8 v1 = frag(Vs, nt * 16 + l16, 4 + quad);
            O[nt] = __builtin_amdgcn_mfma_f32_16x16x32_bf16(pf0, v0, O[nt], 0, 0, 0);
            O[nt] = __builtin_amdgcn_mfma_f32_16x16x32_bf16(pf1, v1, O[nt], 0, 0, 0);
        }
#endif
    }

    // ---- epilogue: O / l, store bf16 (rows aligned with Ol) ----
    float linv[4];
    #pragma unroll
    for (int r = 0; r < 4; ++r) linv[r] = __builtin_amdgcn_rcpf(Ol[r]);

    const int orow0 = i0 + wave * 16 + quad * 4;
    #pragma unroll
    for (int nt = 0; nt < 4; ++nt) {
        const int d = h * HDIM + nt * 16 + l16;
        #pragma unroll
        for (int r = 0; r < 4; ++r)
            attn_out[(size_t)(orow0 + r) * DMODEL + d] = f2bf(O[nt][r] * linv[r]);
    }
}

// ---------------------------------------------------------------------------
extern "C" void kernel_launch(void* const* d_in, const int* in_sizes, int n_in,
                              void* d_out, int out_size, void* d_ws, size_t ws_size,
                              hipStream_t stream)
{
    const float* x     = (const float*)d_in[0];
    const float* Wqkv  = (const float*)d_in[1];
    const float* Wproj = (const float*)d_in[2];
    const float* bproj = (const float*)d_in[3];
    float* out = (float*)d_out;

    ushort* Xb     = (ushort*)d_ws;                          // [4096][768]
    ushort* WqkvT  = Xb    + (size_t)TOKENS * DMODEL;        // [2304][768]
    ushort* WprojT = WqkvT + (size_t)QKV_N * DMODEL;         // [768][768]
    ushort* Qb     = WprojT + (size_t)DMODEL * DMODEL;       // [4096][768]
    ushort* Kb     = Qb    + (size_t)TOKENS * DMODEL;        // [4096][768]
    ushort* Vt     = Kb    + (size_t)TOKENS * DMODEL;        // [768][4096]
    ushort* attn   = Vt    + (size_t)TOKENS * DMODEL;        // [4096][768]

    cvt_bf16_kernel<<<dim3(TOKENS * DMODEL / 4 / 256), 256, 0, stream>>>(
        x, Xb, TOKENS * DMODEL / 4);
    transpose_cvt_kernel<<<dim3(QKV_N / 32, DMODEL / 32), 256, 0, stream>>>(
        Wqkv, WqkvT, DMODEL, QKV_N);
    transpose_cvt_kernel<<<dim3(DMODEL / 32, DMODEL / 32), 256, 0, stream>>>(
        Wproj, WprojT, DMODEL, DMODEL);

    gemm_qkv_mfma<<<dim3(QKV_N / 128, TOKENS / 128), 256, 0, stream>>>(
        Xb, WqkvT, Qb, Kb, Vt);

    attn_mfma_kernel<<<dim3(TOKENS / 64, NHEADS), 256, 0, stream>>>(
        Qb, Kb, Vt, attn);

    gemm_proj_mfma<<<dim3(DMODEL / 64, TOKENS / 128), 256, 0, stream>>>(
        attn, WprojT, bproj, out);
}